// Round 4
// baseline (335.533 us; speedup 1.0000x reference)
//
#include <hip/hip_runtime.h>
#include <math.h>

// Problem constants (match reference.py)
#define HS_D       1024   // input_size
#define HS_MAXLEN  24     // max Huffman path depth
#define HS_NBUCKET 512    // partial-sum buckets in d_ws

// One WAVE per example (4 waves / 256-thr block).
//  - x[n] fragment loaded ONCE into registers (16 floats/lane, coalesced).
//  - whole path metadata row loaded ONCE: lane l<24 holds node[l]/code[l];
//    per-step broadcast via __shfl (v_readlane, no memory in the step loop).
//  - steps processed in batches of 4: 16 global_load_dwordx4 issued
//    back-to-back per batch for memory-level parallelism.
//  - tail steps clamp their node to node0 (cache-hit duplicate) and are
//    masked out at the accumulate; batch loop is wave-uniform in L.
__global__ __launch_bounds__(256, 4) void hsm_wave_kernel(
    const float* __restrict__ x,      // [N_EX, D]
    const float* __restrict__ W,      // [N_DEC, D]
    const int*   __restrict__ t,      // [N_EX]
    const int*   __restrict__ paths,  // [V, MAX_LEN]
    const float* __restrict__ codes,  // [V, MAX_LEN]
    const int*   __restrict__ lens,   // [V]
    float*       __restrict__ ws)     // [HS_NBUCKET] zero-initialized
{
    const int tid  = threadIdx.x;
    const int lane = tid & 63;
    const int n    = blockIdx.x * 4 + (tid >> 6);   // example for this wave

    const int leaf = t[n];          // wave-uniform -> scalar load
    const int L    = lens[leaf];    // wave-uniform

    // x fragment: 16 floats = 4 x float4, coalesced (lane-major).
    const float4* x4 = (const float4*)(x + (size_t)n * HS_D);
    float4 xf[4];
#pragma unroll
    for (int j = 0; j < 4; ++j)
        xf[j] = x4[j * 64 + lane];

    // Whole metadata row in one coalesced shot: lane l<24 holds step l.
    int   node_l = 0;
    float code_l = 0.0f;
    if (lane < HS_MAXLEN) {
        node_l = paths[leaf * HS_MAXLEN + lane];
        code_l = codes[leaf * HS_MAXLEN + lane];
    }

    float local = 0.0f;

    for (int b = 0; b < L; b += 4) {          // wave-uniform loop
        // Broadcast this batch's metadata (readlane; invalid steps -> step 0,
        // duplicate row = cache hit, masked below).
        int   nd[4];
        float cd[4];
#pragma unroll
        for (int s = 0; s < 4; ++s) {
            const int  l = b + s;
            const int  src = (l < L) ? l : 0;
            nd[s] = __shfl(node_l, src);
            cd[s] = __shfl(code_l, src);
        }

        // Issue all 16 W loads before consuming any.
        float4 wf[4][4];
#pragma unroll
        for (int s = 0; s < 4; ++s) {
            const float4* w4 = (const float4*)(W + (size_t)nd[s] * HS_D);
#pragma unroll
            for (int j = 0; j < 4; ++j)
                wf[s][j] = w4[j * 64 + lane];
        }

        // 4 independent partial dots.
        float dot[4];
#pragma unroll
        for (int s = 0; s < 4; ++s) {
            float d = 0.0f;
#pragma unroll
            for (int j = 0; j < 4; ++j) {
                d += xf[j].x * wf[s][j].x + xf[j].y * wf[s][j].y
                   + xf[j].z * wf[s][j].z + xf[j].w * wf[s][j].w;
            }
            dot[s] = d;
        }

        // Interleaved butterfly reductions (4 independent chains).
#pragma unroll
        for (int off = 32; off > 0; off >>= 1) {
#pragma unroll
            for (int s = 0; s < 4; ++s)
                dot[s] += __shfl_down(dot[s], off);
        }

        if (lane == 0) {
#pragma unroll
            for (int s = 0; s < 4; ++s) {
                const float z  = -cd[s] * dot[s];
                const float sp = fmaxf(z, 0.0f) + log1pf(expf(-fabsf(z)));
                local += (b + s < L) ? sp : 0.0f;
            }
        }
    }

    if (lane == 0)
        atomicAdd(&ws[n & (HS_NBUCKET - 1)], local);
}

// Single-wave finish: sum the buckets, write the scalar output.
__global__ __launch_bounds__(64) void hsm_finish_kernel(
    const float* __restrict__ ws, float* __restrict__ out)
{
    const int lane = threadIdx.x;
    float s = 0.0f;
#pragma unroll
    for (int k = 0; k < HS_NBUCKET / 64; ++k)
        s += ws[lane + 64 * k];
#pragma unroll
    for (int off = 32; off > 0; off >>= 1)
        s += __shfl_down(s, off);
    if (lane == 0) out[0] = s;
}

extern "C" void kernel_launch(void* const* d_in, const int* in_sizes, int n_in,
                              void* d_out, int out_size, void* d_ws, size_t ws_size,
                              hipStream_t stream) {
    const float* x     = (const float*)d_in[0];
    const float* W     = (const float*)d_in[1];
    const int*   t     = (const int*)  d_in[2];
    const int*   paths = (const int*)  d_in[3];
    const float* codes = (const float*)d_in[4];
    const int*   lens  = (const int*)  d_in[5];
    float* out = (float*)d_out;
    float* ws  = (float*)d_ws;

    const int n_ex = in_sizes[2];  // t has N_EX elements

    // ws is re-poisoned 0xAA before every timed launch -> zero the buckets.
    hipMemsetAsync(ws, 0, HS_NBUCKET * sizeof(float), stream);

    // One wave per example; 4 waves per 256-thread block.
    hsm_wave_kernel<<<n_ex / 4, 256, 0, stream>>>(x, W, t, paths, codes, lens, ws);
    hsm_finish_kernel<<<1, 64, 0, stream>>>(ws, out);
}